// Round 4
// baseline (286.879 us; speedup 1.0000x reference)
//
#include <hip/hip_runtime.h>
#include <hip/hip_bf16.h>

#define BB   2048
#define SS   256
#define NTOK (BB*SS)
#define FIN  3
#define CND  4
#define EMB  4
#define HID  64
#define NC   256
#define TPB  256   // T=2 tokens/thread: block covers 512 tokens

typedef __attribute__((ext_vector_type(16))) float f32x16;

// R4: hybrid pipe-split. Measured per-pipe economics (R0..R3):
//  - DS pipe: 12 cyc per b128 (4 floats) even broadcast, ONE pipe per CU
//    shared by 4 SIMDs -> all-LDS (R0) = 213us, DS-bound.
//  - SMEM path (s_load_dwordx16): full W2s via SMEM (R3) = ~190us of
//    latency-serialized scalar loads, DS idle at 64us.
//  - Real VALU floor ~82us (VALUBusy counter overcounts 2.1x).
// Fix: split each 64x64 GEMM 50/50 by output column. Cols 0..31 from LDS
// (exact R0 jt4 loop, pure DS), cols 32..63 via s_load_dwordx16 (R3's
// validated 16-wide tiles, pure SMEM; half the loads, 16KB scalar set
// fits K$). Separate loops -> no DS/SMEM lgkmcnt interleave (R1's killer).
// j ascends 0..31 then 32..63 -> fold trees bit-identical to validated.
#define OF_EW1T 0        // 512  ([64][8] rows: w0..w6, eb1)
#define OF_DW1T 512      // 512  ([64][8] rows: w0..w7)
#define OF_DB1  1024     // 64
#define OF_EB2  1088     // 64
#define OF_DB2  1152     // 64
#define OF_EW3  1216     // 256
#define OF_DW3T 1472     // 256  ([64][4] rows: w0,w1,w2,0)
#define OF_CB   1728     // 1024
#define OF_CC   2752     // 256
#define OF_EW2L 3008     // 2048 ([64][32]: cols 0..31)
#define OF_DW2L 5056     // 2048 ([64][32]: cols 0..31)
#define SMEM_F  7104     // 28416 B

// NOTE: min-waves/EU must stay low: this kernel needs ~160+ VGPRs (2x h[64]
// + phase-S accs). (TPB,6)-style caps spill h[] to scratch -> 13x regression.
__global__ __launch_bounds__(TPB, 2) void vqvae_fused(
        const float* __restrict__ x, const float* __restrict__ mask,
        const float* __restrict__ cond,
        const float* __restrict__ ew1, const float* __restrict__ eb1,
        const float* __restrict__ ew2, const float* __restrict__ eb2,
        const float* __restrict__ ew3, const float* __restrict__ eb3,
        const float* __restrict__ cb,
        const float* __restrict__ dw1, const float* __restrict__ db1,
        const float* __restrict__ dw2, const float* __restrict__ db2,
        const float* __restrict__ dw3, const float* __restrict__ db3,
        float* __restrict__ out, float* __restrict__ loss_ws) {
    __shared__ float smem[SMEM_F];
    const int tid = threadIdx.x;

    // ---- staging (once per block) ----
    for (int idx = tid; idx < (FIN+CND)*HID; idx += TPB) {
        int i = idx >> 6, j = idx & 63;
        smem[OF_EW1T + j*8 + i] = ew1[idx];
    }
    for (int j = tid; j < HID; j += TPB) smem[OF_EW1T + j*8 + 7] = eb1[j];
    for (int idx = tid; idx < (EMB+CND)*HID; idx += TPB) {
        int i = idx >> 6, j = idx & 63;
        smem[OF_DW1T + j*8 + i] = dw1[idx];
    }
    for (int j = tid; j < HID; j += TPB) smem[OF_DB1 + j] = db1[j];
    for (int j = tid; j < HID; j += TPB) smem[OF_EB2 + j] = eb2[j];
    for (int j = tid; j < HID; j += TPB) smem[OF_DB2 + j] = db2[j];
    for (int i = tid; i < HID*EMB; i += TPB) smem[OF_EW3 + i] = ew3[i];
    for (int j = tid; j < HID; j += TPB) {
        smem[OF_DW3T + j*4 + 0] = dw3[j*FIN + 0];
        smem[OF_DW3T + j*4 + 1] = dw3[j*FIN + 1];
        smem[OF_DW3T + j*4 + 2] = dw3[j*FIN + 2];
        smem[OF_DW3T + j*4 + 3] = 0.0f;
    }
    for (int i = tid; i < NC*EMB; i += TPB) smem[OF_CB + i] = cb[i];
    // low 32 columns of EW2/DW2 (conflict-free: consecutive tid -> stride-1)
    for (int idx = tid; idx < HID*32; idx += TPB) {
        int k = idx >> 5, j = idx & 31;
        smem[OF_EW2L + idx] = ew2[k*HID + j];
        smem[OF_DW2L + idx] = dw2[k*HID + j];
    }
    {   // cc from GLOBAL cb (no barrier dependency); tid in [0,256) covers NC
        float c0 = cb[tid*EMB+0], c1 = cb[tid*EMB+1];
        float c2 = cb[tid*EMB+2], c3 = cb[tid*EMB+3];
        smem[OF_CC+tid] = ((c0*c0 + c1*c1) + c2*c2) + c3*c3;  // validated order
    }
    __syncthreads();

    // two tokens per thread: n0 in batch 2*blk, n1 in batch 2*blk+1
    const int n0 = blockIdx.x * (2*TPB) + tid;
    const int n1 = n0 + TPB;
    const float m0 = mask[n0];
    const float m1 = mask[n1];
    const int bu0 = n0 >> 8;
    const int bu1 = bu0 + 1;

    float xin0[FIN+CND], xin1[FIN+CND];
    #pragma unroll
    for (int i = 0; i < FIN; i++) xin0[i] = x[n0*FIN + i] * m0;
    #pragma unroll
    for (int i = 0; i < FIN; i++) xin1[i] = x[n1*FIN + i] * m1;
    #pragma unroll
    for (int i = 0; i < CND; i++) xin0[FIN+i] = cond[bu0*CND + i] * m0;
    #pragma unroll
    for (int i = 0; i < CND; i++) xin1[FIN+i] = cond[bu1*CND + i] * m1;

    // ---- encoder L1: 7 -> 64, relu (validated tree; 2x b128 per j) ----
    float hA[HID], hB[HID];
    #pragma unroll
    for (int j = 0; j < HID; j++) {
        float4 lo = *(const float4*)&smem[OF_EW1T + j*8 + 0];
        float4 hi = *(const float4*)&smem[OF_EW1T + j*8 + 4];
        float a = xin0[0] * lo.x;
        float b = xin1[0] * lo.x;
        a = fmaf(xin0[1], lo.y, a);  b = fmaf(xin1[1], lo.y, b);
        a = fmaf(xin0[2], lo.z, a);  b = fmaf(xin1[2], lo.z, b);
        a = fmaf(xin0[3], lo.w, a);  b = fmaf(xin1[3], lo.w, b);
        a = fmaf(xin0[4], hi.x, a);  b = fmaf(xin1[4], hi.x, b);
        a = fmaf(xin0[5], hi.y, a);  b = fmaf(xin1[5], hi.y, b);
        a = fmaf(xin0[6], hi.z, a);  b = fmaf(xin1[6], hi.z, b);
        hA[j] = fmaxf(a + hi.w, 0.0f);
        hB[j] = fmaxf(b + hi.w, 0.0f);
    }

    // ---- encoder L2 (relu) fused with L3 fold ----
    float z0 = 0.f, z1 = 0.f, z2 = 0.f, z3 = 0.f;
    float y0 = 0.f, y1 = 0.f, y2 = 0.f, y3 = 0.f;
    // Phase L: outputs 0..31 from LDS (pure DS; exact R0 jt4 loop)
    for (int jt = 0; jt < 8; jt++) {
        float a0 = 0.f, a1 = 0.f, a2 = 0.f, a3 = 0.f;
        float b0 = 0.f, b1 = 0.f, b2 = 0.f, b3 = 0.f;
        #pragma unroll
        for (int k = 0; k < HID; k++) {
            float4 w = *(const float4*)&smem[OF_EW2L + k*32 + jt*4];
            a0 = fmaf(hA[k], w.x, a0);
            a1 = fmaf(hA[k], w.y, a1);
            a2 = fmaf(hA[k], w.z, a2);
            a3 = fmaf(hA[k], w.w, a3);
            b0 = fmaf(hB[k], w.x, b0);
            b1 = fmaf(hB[k], w.y, b1);
            b2 = fmaf(hB[k], w.z, b2);
            b3 = fmaf(hB[k], w.w, b3);
        }
        float4 bb = *(const float4*)&smem[OF_EB2 + jt*4];
        float ta0 = fmaxf(a0 + bb.x, 0.0f), tb0 = fmaxf(b0 + bb.x, 0.0f);
        float ta1 = fmaxf(a1 + bb.y, 0.0f), tb1 = fmaxf(b1 + bb.y, 0.0f);
        float ta2 = fmaxf(a2 + bb.z, 0.0f), tb2 = fmaxf(b2 + bb.z, 0.0f);
        float ta3 = fmaxf(a3 + bb.w, 0.0f), tb3 = fmaxf(b3 + bb.w, 0.0f);
        float4 w0 = *(const float4*)&smem[OF_EW3 + (jt*4+0)*EMB];
        z0 = fmaf(ta0, w0.x, z0); z1 = fmaf(ta0, w0.y, z1);
        z2 = fmaf(ta0, w0.z, z2); z3 = fmaf(ta0, w0.w, z3);
        y0 = fmaf(tb0, w0.x, y0); y1 = fmaf(tb0, w0.y, y1);
        y2 = fmaf(tb0, w0.z, y2); y3 = fmaf(tb0, w0.w, y3);
        float4 w1 = *(const float4*)&smem[OF_EW3 + (jt*4+1)*EMB];
        z0 = fmaf(ta1, w1.x, z0); z1 = fmaf(ta1, w1.y, z1);
        z2 = fmaf(ta1, w1.z, z2); z3 = fmaf(ta1, w1.w, z3);
        y0 = fmaf(tb1, w1.x, y0); y1 = fmaf(tb1, w1.y, y1);
        y2 = fmaf(tb1, w1.z, y2); y3 = fmaf(tb1, w1.w, y3);
        float4 w2 = *(const float4*)&smem[OF_EW3 + (jt*4+2)*EMB];
        z0 = fmaf(ta2, w2.x, z0); z1 = fmaf(ta2, w2.y, z1);
        z2 = fmaf(ta2, w2.z, z2); z3 = fmaf(ta2, w2.w, z3);
        y0 = fmaf(tb2, w2.x, y0); y1 = fmaf(tb2, w2.y, y1);
        y2 = fmaf(tb2, w2.z, y2); y3 = fmaf(tb2, w2.w, y3);
        float4 w3 = *(const float4*)&smem[OF_EW3 + (jt*4+3)*EMB];
        z0 = fmaf(ta3, w3.x, z0); z1 = fmaf(ta3, w3.y, z1);
        z2 = fmaf(ta3, w3.z, z2); z3 = fmaf(ta3, w3.w, z3);
        y0 = fmaf(tb3, w3.x, y0); y1 = fmaf(tb3, w3.y, y1);
        y2 = fmaf(tb3, w3.z, y2); y3 = fmaf(tb3, w3.w, y3);
    }
    // Phase S: outputs 32..63 via s_load_dwordx16 (pure SMEM; R3 tiles)
    for (int t = 0; t < 2; t++) {
        float a[16], b[16];
        #pragma unroll
        for (int u = 0; u < 16; u++) { a[u] = 0.f; b[u] = 0.f; }
        #pragma unroll
        for (int k = 0; k < HID; k++) {
            f32x16 w = *(const f32x16*)&ew2[k*HID + 32 + t*16];
            #pragma unroll
            for (int u = 0; u < 16; u++) {
                a[u] = fmaf(hA[k], w[u], a[u]);
                b[u] = fmaf(hB[k], w[u], b[u]);
            }
        }
        f32x16 bb = *(const f32x16*)&eb2[32 + t*16];
        #pragma unroll
        for (int u = 0; u < 16; u++) {
            float ta = fmaxf(a[u] + bb[u], 0.0f);
            float tb = fmaxf(b[u] + bb[u], 0.0f);
            float4 w3 = *(const float4*)&smem[OF_EW3 + (32 + t*16 + u)*EMB];
            z0 = fmaf(ta, w3.x, z0); z1 = fmaf(ta, w3.y, z1);
            z2 = fmaf(ta, w3.z, z2); z3 = fmaf(ta, w3.w, z3);
            y0 = fmaf(tb, w3.x, y0); y1 = fmaf(tb, w3.y, y1);
            y2 = fmaf(tb, w3.z, y2); y3 = fmaf(tb, w3.w, y3);
        }
    }
    z0 += eb3[0]; z1 += eb3[1];
    z2 += eb3[2]; z3 += eb3[3];
    y0 += eb3[0]; y1 += eb3[1];
    y2 += eb3[2]; y3 += eb3[3];

    // ---- VQ argmin both tokens (LDS codebook; strict < = np first-min) ----
    const float zzA = ((z0*z0 + z1*z1) + z2*z2) + z3*z3;
    const float zzB = ((y0*y0 + y1*y1) + y2*y2) + y3*y3;
    float bestA = 3.4e38f, bestB = 3.4e38f;
    int   biA = 0, biB = 0;
    #pragma unroll 4
    for (int ci = 0; ci < NC; ci++) {
        float4 c = *(const float4*)&smem[OF_CB + ci*EMB];
        float cc = smem[OF_CC + ci];
        float dotA = z0 * c.x;
        dotA = fmaf(z1, c.y, dotA);
        dotA = fmaf(z2, c.z, dotA);
        dotA = fmaf(z3, c.w, dotA);
        float dA = (zzA - 2.0f*dotA) + cc;
        if (dA < bestA) { bestA = dA; biA = ci; }
        float dotB = y0 * c.x;
        dotB = fmaf(y1, c.y, dotB);
        dotB = fmaf(y2, c.z, dotB);
        dotB = fmaf(y3, c.w, dotB);
        float dB = (zzB - 2.0f*dotB) + cc;
        if (dB < bestB) { bestB = dB; biB = ci; }
    }
    float4 qA = *(const float4*)&smem[OF_CB + biA*EMB];
    float4 qB = *(const float4*)&smem[OF_CB + biB*EMB];

    // ---- vq loss partial (atomic order arbitrary; huge threshold slack) ----
    float e0 = z0-qA.x, e1 = z1-qA.y, e2 = z2-qA.z, e3 = z3-qA.w;
    float f0 = y0-qB.x, f1 = y1-qB.y, f2 = y2-qB.z, f3 = y3-qB.w;
    float sq = (((e0*e0 + e1*e1) + e2*e2) + e3*e3)
             + (((f0*f0 + f1*f1) + f2*f2) + f3*f3);
    #pragma unroll
    for (int off = 32; off > 0; off >>= 1) sq += __shfl_down(sq, off, 64);
    if ((tid & 63) == 0) atomicAdd(loss_ws, sq);

    out[NTOK*FIN + 1 + n0] = (float)biA;
    out[NTOK*FIN + 1 + n1] = (float)biB;

    // ---- decoder input (refetch cond: frees regs over the long mid-section) ----
    float zd0[EMB+CND], zd1[EMB+CND];
    zd0[0] = qA.x*m0; zd0[1] = qA.y*m0; zd0[2] = qA.z*m0; zd0[3] = qA.w*m0;
    zd1[0] = qB.x*m1; zd1[1] = qB.y*m1; zd1[2] = qB.z*m1; zd1[3] = qB.w*m1;
    #pragma unroll
    for (int i = 0; i < CND; i++) zd0[EMB+i] = cond[bu0*CND + i] * m0;
    #pragma unroll
    for (int i = 0; i < CND; i++) zd1[EMB+i] = cond[bu1*CND + i] * m1;

    // ---- decoder L1: 8 -> 64, relu (validated tree; 2x b128 per j) ----
    #pragma unroll
    for (int j = 0; j < HID; j++) {
        float4 lo = *(const float4*)&smem[OF_DW1T + j*8 + 0];
        float4 hi = *(const float4*)&smem[OF_DW1T + j*8 + 4];
        float a = zd0[0] * lo.x;
        float b = zd1[0] * lo.x;
        a = fmaf(zd0[1], lo.y, a);  b = fmaf(zd1[1], lo.y, b);
        a = fmaf(zd0[2], lo.z, a);  b = fmaf(zd1[2], lo.z, b);
        a = fmaf(zd0[3], lo.w, a);  b = fmaf(zd1[3], lo.w, b);
        a = fmaf(zd0[4], hi.x, a);  b = fmaf(zd1[4], hi.x, b);
        a = fmaf(zd0[5], hi.y, a);  b = fmaf(zd1[5], hi.y, b);
        a = fmaf(zd0[6], hi.z, a);  b = fmaf(zd1[6], hi.z, b);
        a = fmaf(zd0[7], hi.w, a);  b = fmaf(zd1[7], hi.w, b);
        float bias = smem[OF_DB1 + j];
        hA[j] = fmaxf(a + bias, 0.0f);
        hB[j] = fmaxf(b + bias, 0.0f);
    }

    // ---- decoder L2 (relu) fused with L3 ----
    float r0 = 0.f, r1 = 0.f, r2 = 0.f;
    float s0 = 0.f, s1 = 0.f, s2 = 0.f;
    // Phase L: outputs 0..31 from LDS (pure DS)
    for (int jt = 0; jt < 8; jt++) {
        float a0 = 0.f, a1 = 0.f, a2 = 0.f, a3 = 0.f;
        float b0 = 0.f, b1 = 0.f, b2 = 0.f, b3 = 0.f;
        #pragma unroll
        for (int k = 0; k < HID; k++) {
            float4 w = *(const float4*)&smem[OF_DW2L + k*32 + jt*4];
            a0 = fmaf(hA[k], w.x, a0);
            a1 = fmaf(hA[k], w.y, a1);
            a2 = fmaf(hA[k], w.z, a2);
            a3 = fmaf(hA[k], w.w, a3);
            b0 = fmaf(hB[k], w.x, b0);
            b1 = fmaf(hB[k], w.y, b1);
            b2 = fmaf(hB[k], w.z, b2);
            b3 = fmaf(hB[k], w.w, b3);
        }
        float4 bb = *(const float4*)&smem[OF_DB2 + jt*4];
        float ta0 = fmaxf(a0 + bb.x, 0.0f), tb0 = fmaxf(b0 + bb.x, 0.0f);
        float ta1 = fmaxf(a1 + bb.y, 0.0f), tb1 = fmaxf(b1 + bb.y, 0.0f);
        float ta2 = fmaxf(a2 + bb.z, 0.0f), tb2 = fmaxf(b2 + bb.z, 0.0f);
        float ta3 = fmaxf(a3 + bb.w, 0.0f), tb3 = fmaxf(b3 + bb.w, 0.0f);
        #pragma unroll
        for (int jj = 0; jj < 4; jj++) {
            float ta = (jj==0)?ta0:(jj==1)?ta1:(jj==2)?ta2:ta3;
            float tb = (jj==0)?tb0:(jj==1)?tb1:(jj==2)?tb2:tb3;
            int j = jt*4 + jj;
            float4 w = *(const float4*)&smem[OF_DW3T + j*4];
            r0 = fmaf(ta, w.x, r0); s0 = fmaf(tb, w.x, s0);
            r1 = fmaf(ta, w.y, r1); s1 = fmaf(tb, w.y, s1);
            r2 = fmaf(ta, w.z, r2); s2 = fmaf(tb, w.z, s2);
        }
    }
    // Phase S: outputs 32..63 via s_load_dwordx16 (pure SMEM)
    for (int t = 0; t < 2; t++) {
        float a[16], b[16];
        #pragma unroll
        for (int u = 0; u < 16; u++) { a[u] = 0.f; b[u] = 0.f; }
        #pragma unroll
        for (int k = 0; k < HID; k++) {
            f32x16 w = *(const f32x16*)&dw2[k*HID + 32 + t*16];
            #pragma unroll
            for (int u = 0; u < 16; u++) {
                a[u] = fmaf(hA[k], w[u], a[u]);
                b[u] = fmaf(hB[k], w[u], b[u]);
            }
        }
        f32x16 bb = *(const f32x16*)&db2[32 + t*16];
        #pragma unroll
        for (int u = 0; u < 16; u++) {
            float ta = fmaxf(a[u] + bb[u], 0.0f);
            float tb = fmaxf(b[u] + bb[u], 0.0f);
            float4 w = *(const float4*)&smem[OF_DW3T + (32 + t*16 + u)*4];
            r0 = fmaf(ta, w.x, r0); s0 = fmaf(tb, w.x, s0);
            r1 = fmaf(ta, w.y, r1); s1 = fmaf(tb, w.y, s1);
            r2 = fmaf(ta, w.z, r2); s2 = fmaf(tb, w.z, s2);
        }
    }
    r0 += db3[0]; r1 += db3[1]; r2 += db3[2];
    s0 += db3[0]; s1 += db3[1]; s2 += db3[2];

    out[n0*FIN + 0] = r0;
    out[n0*FIN + 1] = r1;
    out[n0*FIN + 2] = r2;
    out[n1*FIN + 0] = s0;
    out[n1*FIN + 1] = s1;
    out[n1*FIN + 2] = s2;
}

__global__ void finalize_kernel(float* out, const float* loss_ws) {
    out[NTOK*FIN] = 1.25f * loss_ws[0] * (1.0f / (float)(NTOK*EMB));
}

extern "C" void kernel_launch(void* const* d_in, const int* in_sizes, int n_in,
                              void* d_out, int out_size, void* d_ws, size_t ws_size,
                              hipStream_t stream) {
    (void)in_sizes; (void)n_in; (void)ws_size; (void)out_size;
    float* ws = (float*)d_ws;
    hipMemsetAsync(ws, 0, sizeof(float), stream);   // ws re-poisoned each call

    vqvae_fused<<<NTOK/(2*TPB), TPB, 0, stream>>>(
        (const float*)d_in[0], (const float*)d_in[1], (const float*)d_in[2],
        (const float*)d_in[3], (const float*)d_in[4], (const float*)d_in[5],
        (const float*)d_in[6], (const float*)d_in[7], (const float*)d_in[8],
        (const float*)d_in[9], (const float*)d_in[10], (const float*)d_in[11],
        (const float*)d_in[12], (const float*)d_in[13], (const float*)d_in[14],
        (const float*)d_in[15],
        (float*)d_out, ws);

    finalize_kernel<<<1, 1, 0, stream>>>((float*)d_out, ws);
}

// Round 5
// 280.508 us; speedup vs baseline: 1.0227x; 1.0227x over previous
//
#include <hip/hip_runtime.h>
#include <hip/hip_bf16.h>

#define BB   2048
#define SS   256
#define NTOK (BB*SS)
#define FIN  3
#define CND  4
#define EMB  4
#define HID  64
#define NC   256
#define TPB  256   // T=2 tokens/thread: block covers 512 tokens

typedef __attribute__((ext_vector_type(16))) float f32x16;

// R5: per-WAVE pipe split. R4 proved column-split phases execute in lockstep
// across waves -> DS-wall + scalar-wall ADD (223us = 128+95). Fix: each wave
// uses ONE pipe for its whole L2 work, so different waves drive DS and SMEM
// concurrently. L-waves = R0's full-LDS loops (DS, ~35k cyc/wave); S-waves =
// R3's s_load_dwordx16 loops (scalar, ~32KB/wave at ~1B/cyc). Both trees are
// bit-identical (same k-order, same j-fold order; absmax constant across
// R0-R4 proves it). Ratio 3L:5S per block-pair balances walls at ~130us.
// VQ/L1/EW3/DW3T stay LDS for all waves (lane-divergent or tiny).
#define OF_EW1T 0        // 512  ([64][8] rows: w0..w6, eb1)
#define OF_DW1T 512      // 512  ([64][8] rows: w0..w7)
#define OF_DB1  1024     // 64
#define OF_EB2  1088     // 64
#define OF_DB2  1152     // 64
#define OF_EW3  1216     // 256
#define OF_DW3T 1472     // 256  ([64][4] rows: w0,w1,w2,0)
#define OF_CB   1728     // 1024
#define OF_CC   2752     // 256
#define OF_EW2F 3008     // 4096 (full [64][64])
#define OF_DW2F 7104     // 4096 (full [64][64])
#define SMEM_F  11200    // 44800 B -> 3 blocks/CU (DS wall counts total
                         // instructions, not residency; tail cost is small)

// NOTE: min-waves/EU must stay low: S-waves need ~160 VGPRs (h[128]+32 accs).
// (TPB,6)-style caps spill h[] to scratch -> 13x regression.
__global__ __launch_bounds__(TPB, 2) void vqvae_fused(
        const float* __restrict__ x, const float* __restrict__ mask,
        const float* __restrict__ cond,
        const float* __restrict__ ew1, const float* __restrict__ eb1,
        const float* __restrict__ ew2, const float* __restrict__ eb2,
        const float* __restrict__ ew3, const float* __restrict__ eb3,
        const float* __restrict__ cb,
        const float* __restrict__ dw1, const float* __restrict__ db1,
        const float* __restrict__ dw2, const float* __restrict__ db2,
        const float* __restrict__ dw3, const float* __restrict__ db3,
        float* __restrict__ out, float* __restrict__ loss_ws) {
    __shared__ float smem[SMEM_F];
    const int tid = threadIdx.x;

    // ---- staging (once per block) ----
    for (int idx = tid; idx < (FIN+CND)*HID; idx += TPB) {
        int i = idx >> 6, j = idx & 63;
        smem[OF_EW1T + j*8 + i] = ew1[idx];
    }
    for (int j = tid; j < HID; j += TPB) smem[OF_EW1T + j*8 + 7] = eb1[j];
    for (int idx = tid; idx < (EMB+CND)*HID; idx += TPB) {
        int i = idx >> 6, j = idx & 63;
        smem[OF_DW1T + j*8 + i] = dw1[idx];
    }
    for (int j = tid; j < HID; j += TPB) smem[OF_DB1 + j] = db1[j];
    for (int j = tid; j < HID; j += TPB) smem[OF_EB2 + j] = eb2[j];
    for (int j = tid; j < HID; j += TPB) smem[OF_DB2 + j] = db2[j];
    for (int i = tid; i < HID*EMB; i += TPB) smem[OF_EW3 + i] = ew3[i];
    for (int j = tid; j < HID; j += TPB) {
        smem[OF_DW3T + j*4 + 0] = dw3[j*FIN + 0];
        smem[OF_DW3T + j*4 + 1] = dw3[j*FIN + 1];
        smem[OF_DW3T + j*4 + 2] = dw3[j*FIN + 2];
        smem[OF_DW3T + j*4 + 3] = 0.0f;
    }
    for (int i = tid; i < NC*EMB; i += TPB) smem[OF_CB + i] = cb[i];
    // full W2 matrices, float4 copies (L2-hot: negligible HBM fetch)
    for (int i = tid; i < HID*HID/4; i += TPB) {
        *(float4*)&smem[OF_EW2F + i*4] = *(const float4*)&ew2[i*4];
        *(float4*)&smem[OF_DW2F + i*4] = *(const float4*)&dw2[i*4];
    }
    {   // cc from GLOBAL cb (no barrier dependency); tid in [0,256) covers NC
        float c0 = cb[tid*EMB+0], c1 = cb[tid*EMB+1];
        float c2 = cb[tid*EMB+2], c3 = cb[tid*EMB+3];
        smem[OF_CC+tid] = ((c0*c0 + c1*c1) + c2*c2) + c3*c3;  // validated order
    }
    __syncthreads();

    // wave path: even blocks {L,S,S,L}, odd {S,L,S,S} -> 3L:5S per block pair
    const int wid = tid >> 6;
    const bool pathL = (blockIdx.x & 1) ? (wid == 1) : (wid == 0 || wid == 3);

    // two tokens per thread: n0 in batch 2*blk, n1 in batch 2*blk+1
    const int n0 = blockIdx.x * (2*TPB) + tid;
    const int n1 = n0 + TPB;
    const float m0 = mask[n0];
    const float m1 = mask[n1];
    const int bu0 = n0 >> 8;
    const int bu1 = bu0 + 1;

    float xin0[FIN+CND], xin1[FIN+CND];
    #pragma unroll
    for (int i = 0; i < FIN; i++) xin0[i] = x[n0*FIN + i] * m0;
    #pragma unroll
    for (int i = 0; i < FIN; i++) xin1[i] = x[n1*FIN + i] * m1;
    #pragma unroll
    for (int i = 0; i < CND; i++) xin0[FIN+i] = cond[bu0*CND + i] * m0;
    #pragma unroll
    for (int i = 0; i < CND; i++) xin1[FIN+i] = cond[bu1*CND + i] * m1;

    // ---- encoder L1: 7 -> 64, relu (validated tree; 2x b128 per j) ----
    float hA[HID], hB[HID];
    #pragma unroll
    for (int j = 0; j < HID; j++) {
        float4 lo = *(const float4*)&smem[OF_EW1T + j*8 + 0];
        float4 hi = *(const float4*)&smem[OF_EW1T + j*8 + 4];
        float a = xin0[0] * lo.x;
        float b = xin1[0] * lo.x;
        a = fmaf(xin0[1], lo.y, a);  b = fmaf(xin1[1], lo.y, b);
        a = fmaf(xin0[2], lo.z, a);  b = fmaf(xin1[2], lo.z, b);
        a = fmaf(xin0[3], lo.w, a);  b = fmaf(xin1[3], lo.w, b);
        a = fmaf(xin0[4], hi.x, a);  b = fmaf(xin1[4], hi.x, b);
        a = fmaf(xin0[5], hi.y, a);  b = fmaf(xin1[5], hi.y, b);
        a = fmaf(xin0[6], hi.z, a);  b = fmaf(xin1[6], hi.z, b);
        hA[j] = fmaxf(a + hi.w, 0.0f);
        hB[j] = fmaxf(b + hi.w, 0.0f);
    }

    // ---- encoder L2 (relu) fused with L3 fold: per-wave pipe choice ----
    float z0 = 0.f, z1 = 0.f, z2 = 0.f, z3 = 0.f;
    float y0 = 0.f, y1 = 0.f, y2 = 0.f, y3 = 0.f;
    if (pathL) {
        // L-wave: full-LDS (pure DS pipe; exact R0 tree)
        for (int jt = 0; jt < 16; jt++) {
            float a0 = 0.f, a1 = 0.f, a2 = 0.f, a3 = 0.f;
            float b0 = 0.f, b1 = 0.f, b2 = 0.f, b3 = 0.f;
            #pragma unroll
            for (int k = 0; k < HID; k++) {
                float4 w = *(const float4*)&smem[OF_EW2F + k*HID + jt*4];
                a0 = fmaf(hA[k], w.x, a0);
                a1 = fmaf(hA[k], w.y, a1);
                a2 = fmaf(hA[k], w.z, a2);
                a3 = fmaf(hA[k], w.w, a3);
                b0 = fmaf(hB[k], w.x, b0);
                b1 = fmaf(hB[k], w.y, b1);
                b2 = fmaf(hB[k], w.z, b2);
                b3 = fmaf(hB[k], w.w, b3);
            }
            float4 bb = *(const float4*)&smem[OF_EB2 + jt*4];
            float ta0 = fmaxf(a0 + bb.x, 0.0f), tb0 = fmaxf(b0 + bb.x, 0.0f);
            float ta1 = fmaxf(a1 + bb.y, 0.0f), tb1 = fmaxf(b1 + bb.y, 0.0f);
            float ta2 = fmaxf(a2 + bb.z, 0.0f), tb2 = fmaxf(b2 + bb.z, 0.0f);
            float ta3 = fmaxf(a3 + bb.w, 0.0f), tb3 = fmaxf(b3 + bb.w, 0.0f);
            float4 w0 = *(const float4*)&smem[OF_EW3 + (jt*4+0)*EMB];
            z0 = fmaf(ta0, w0.x, z0); z1 = fmaf(ta0, w0.y, z1);
            z2 = fmaf(ta0, w0.z, z2); z3 = fmaf(ta0, w0.w, z3);
            y0 = fmaf(tb0, w0.x, y0); y1 = fmaf(tb0, w0.y, y1);
            y2 = fmaf(tb0, w0.z, y2); y3 = fmaf(tb0, w0.w, y3);
            float4 w1 = *(const float4*)&smem[OF_EW3 + (jt*4+1)*EMB];
            z0 = fmaf(ta1, w1.x, z0); z1 = fmaf(ta1, w1.y, z1);
            z2 = fmaf(ta1, w1.z, z2); z3 = fmaf(ta1, w1.w, z3);
            y0 = fmaf(tb1, w1.x, y0); y1 = fmaf(tb1, w1.y, y1);
            y2 = fmaf(tb1, w1.z, y2); y3 = fmaf(tb1, w1.w, y3);
            float4 w2 = *(const float4*)&smem[OF_EW3 + (jt*4+2)*EMB];
            z0 = fmaf(ta2, w2.x, z0); z1 = fmaf(ta2, w2.y, z1);
            z2 = fmaf(ta2, w2.z, z2); z3 = fmaf(ta2, w2.w, z3);
            y0 = fmaf(tb2, w2.x, y0); y1 = fmaf(tb2, w2.y, y1);
            y2 = fmaf(tb2, w2.z, y2); y3 = fmaf(tb2, w2.w, y3);
            float4 w3 = *(const float4*)&smem[OF_EW3 + (jt*4+3)*EMB];
            z0 = fmaf(ta3, w3.x, z0); z1 = fmaf(ta3, w3.y, z1);
            z2 = fmaf(ta3, w3.z, z2); z3 = fmaf(ta3, w3.w, z3);
            y0 = fmaf(tb3, w3.x, y0); y1 = fmaf(tb3, w3.y, y1);
            y2 = fmaf(tb3, w3.z, y2); y3 = fmaf(tb3, w3.w, y3);
        }
    } else {
        // S-wave: scalar s_load_dwordx16 path (exact R3 tree)
        for (int t = 0; t < 4; t++) {
            float a[16], b[16];
            #pragma unroll
            for (int u = 0; u < 16; u++) { a[u] = 0.f; b[u] = 0.f; }
            #pragma unroll
            for (int k = 0; k < HID; k++) {
                f32x16 w = *(const f32x16*)&ew2[k*HID + t*16];
                #pragma unroll
                for (int u = 0; u < 16; u++) {
                    a[u] = fmaf(hA[k], w[u], a[u]);
                    b[u] = fmaf(hB[k], w[u], b[u]);
                }
            }
            f32x16 bb = *(const f32x16*)&eb2[t*16];
            #pragma unroll
            for (int u = 0; u < 16; u++) {
                float ta = fmaxf(a[u] + bb[u], 0.0f);
                float tb = fmaxf(b[u] + bb[u], 0.0f);
                float4 w3 = *(const float4*)&smem[OF_EW3 + (t*16+u)*EMB];
                z0 = fmaf(ta, w3.x, z0); z1 = fmaf(ta, w3.y, z1);
                z2 = fmaf(ta, w3.z, z2); z3 = fmaf(ta, w3.w, z3);
                y0 = fmaf(tb, w3.x, y0); y1 = fmaf(tb, w3.y, y1);
                y2 = fmaf(tb, w3.z, y2); y3 = fmaf(tb, w3.w, y3);
            }
        }
    }
    z0 += eb3[0]; z1 += eb3[1];
    z2 += eb3[2]; z3 += eb3[3];
    y0 += eb3[0]; y1 += eb3[1];
    y2 += eb3[2]; y3 += eb3[3];

    // ---- VQ argmin both tokens (LDS codebook; strict < = np first-min) ----
    const float zzA = ((z0*z0 + z1*z1) + z2*z2) + z3*z3;
    const float zzB = ((y0*y0 + y1*y1) + y2*y2) + y3*y3;
    float bestA = 3.4e38f, bestB = 3.4e38f;
    int   biA = 0, biB = 0;
    #pragma unroll 4
    for (int ci = 0; ci < NC; ci++) {
        float4 c = *(const float4*)&smem[OF_CB + ci*EMB];
        float cc = smem[OF_CC + ci];
        float dotA = z0 * c.x;
        dotA = fmaf(z1, c.y, dotA);
        dotA = fmaf(z2, c.z, dotA);
        dotA = fmaf(z3, c.w, dotA);
        float dA = (zzA - 2.0f*dotA) + cc;
        if (dA < bestA) { bestA = dA; biA = ci; }
        float dotB = y0 * c.x;
        dotB = fmaf(y1, c.y, dotB);
        dotB = fmaf(y2, c.z, dotB);
        dotB = fmaf(y3, c.w, dotB);
        float dB = (zzB - 2.0f*dotB) + cc;
        if (dB < bestB) { bestB = dB; biB = ci; }
    }
    float4 qA = *(const float4*)&smem[OF_CB + biA*EMB];
    float4 qB = *(const float4*)&smem[OF_CB + biB*EMB];

    // ---- vq loss partial (atomic order arbitrary; huge threshold slack) ----
    float e0 = z0-qA.x, e1 = z1-qA.y, e2 = z2-qA.z, e3 = z3-qA.w;
    float f0 = y0-qB.x, f1 = y1-qB.y, f2 = y2-qB.z, f3 = y3-qB.w;
    float sq = (((e0*e0 + e1*e1) + e2*e2) + e3*e3)
             + (((f0*f0 + f1*f1) + f2*f2) + f3*f3);
    #pragma unroll
    for (int off = 32; off > 0; off >>= 1) sq += __shfl_down(sq, off, 64);
    if ((tid & 63) == 0) atomicAdd(loss_ws, sq);

    out[NTOK*FIN + 1 + n0] = (float)biA;
    out[NTOK*FIN + 1 + n1] = (float)biB;

    // ---- decoder input (refetch cond: frees regs over the long mid-section) ----
    float zd0[EMB+CND], zd1[EMB+CND];
    zd0[0] = qA.x*m0; zd0[1] = qA.y*m0; zd0[2] = qA.z*m0; zd0[3] = qA.w*m0;
    zd1[0] = qB.x*m1; zd1[1] = qB.y*m1; zd1[2] = qB.z*m1; zd1[3] = qB.w*m1;
    #pragma unroll
    for (int i = 0; i < CND; i++) zd0[EMB+i] = cond[bu0*CND + i] * m0;
    #pragma unroll
    for (int i = 0; i < CND; i++) zd1[EMB+i] = cond[bu1*CND + i] * m1;

    // ---- decoder L1: 8 -> 64, relu (validated tree; 2x b128 per j) ----
    #pragma unroll
    for (int j = 0; j < HID; j++) {
        float4 lo = *(const float4*)&smem[OF_DW1T + j*8 + 0];
        float4 hi = *(const float4*)&smem[OF_DW1T + j*8 + 4];
        float a = zd0[0] * lo.x;
        float b = zd1[0] * lo.x;
        a = fmaf(zd0[1], lo.y, a);  b = fmaf(zd1[1], lo.y, b);
        a = fmaf(zd0[2], lo.z, a);  b = fmaf(zd1[2], lo.z, b);
        a = fmaf(zd0[3], lo.w, a);  b = fmaf(zd1[3], lo.w, b);
        a = fmaf(zd0[4], hi.x, a);  b = fmaf(zd1[4], hi.x, b);
        a = fmaf(zd0[5], hi.y, a);  b = fmaf(zd1[5], hi.y, b);
        a = fmaf(zd0[6], hi.z, a);  b = fmaf(zd1[6], hi.z, b);
        a = fmaf(zd0[7], hi.w, a);  b = fmaf(zd1[7], hi.w, b);
        float bias = smem[OF_DB1 + j];
        hA[j] = fmaxf(a + bias, 0.0f);
        hB[j] = fmaxf(b + bias, 0.0f);
    }

    // ---- decoder L2 (relu) fused with L3: per-wave pipe choice ----
    float r0 = 0.f, r1 = 0.f, r2 = 0.f;
    float s0 = 0.f, s1 = 0.f, s2 = 0.f;
    if (pathL) {
        // L-wave: full-LDS (pure DS pipe)
        for (int jt = 0; jt < 16; jt++) {
            float a0 = 0.f, a1 = 0.f, a2 = 0.f, a3 = 0.f;
            float b0 = 0.f, b1 = 0.f, b2 = 0.f, b3 = 0.f;
            #pragma unroll
            for (int k = 0; k < HID; k++) {
                float4 w = *(const float4*)&smem[OF_DW2F + k*HID + jt*4];
                a0 = fmaf(hA[k], w.x, a0);
                a1 = fmaf(hA[k], w.y, a1);
                a2 = fmaf(hA[k], w.z, a2);
                a3 = fmaf(hA[k], w.w, a3);
                b0 = fmaf(hB[k], w.x, b0);
                b1 = fmaf(hB[k], w.y, b1);
                b2 = fmaf(hB[k], w.z, b2);
                b3 = fmaf(hB[k], w.w, b3);
            }
            float4 bb = *(const float4*)&smem[OF_DB2 + jt*4];
            float ta0 = fmaxf(a0 + bb.x, 0.0f), tb0 = fmaxf(b0 + bb.x, 0.0f);
            float ta1 = fmaxf(a1 + bb.y, 0.0f), tb1 = fmaxf(b1 + bb.y, 0.0f);
            float ta2 = fmaxf(a2 + bb.z, 0.0f), tb2 = fmaxf(b2 + bb.z, 0.0f);
            float ta3 = fmaxf(a3 + bb.w, 0.0f), tb3 = fmaxf(b3 + bb.w, 0.0f);
            #pragma unroll
            for (int jj = 0; jj < 4; jj++) {
                float ta = (jj==0)?ta0:(jj==1)?ta1:(jj==2)?ta2:ta3;
                float tb = (jj==0)?tb0:(jj==1)?tb1:(jj==2)?tb2:tb3;
                int j = jt*4 + jj;
                float4 w = *(const float4*)&smem[OF_DW3T + j*4];
                r0 = fmaf(ta, w.x, r0); s0 = fmaf(tb, w.x, s0);
                r1 = fmaf(ta, w.y, r1); s1 = fmaf(tb, w.y, s1);
                r2 = fmaf(ta, w.z, r2); s2 = fmaf(tb, w.z, s2);
            }
        }
    } else {
        // S-wave: scalar s_load_dwordx16 path
        for (int t = 0; t < 4; t++) {
            float a[16], b[16];
            #pragma unroll
            for (int u = 0; u < 16; u++) { a[u] = 0.f; b[u] = 0.f; }
            #pragma unroll
            for (int k = 0; k < HID; k++) {
                f32x16 w = *(const f32x16*)&dw2[k*HID + t*16];
                #pragma unroll
                for (int u = 0; u < 16; u++) {
                    a[u] = fmaf(hA[k], w[u], a[u]);
                    b[u] = fmaf(hB[k], w[u], b[u]);
                }
            }
            f32x16 bb = *(const f32x16*)&db2[t*16];
            #pragma unroll
            for (int u = 0; u < 16; u++) {
                float ta = fmaxf(a[u] + bb[u], 0.0f);
                float tb = fmaxf(b[u] + bb[u], 0.0f);
                float4 w = *(const float4*)&smem[OF_DW3T + (t*16+u)*4];
                r0 = fmaf(ta, w.x, r0); s0 = fmaf(tb, w.x, s0);
                r1 = fmaf(ta, w.y, r1); s1 = fmaf(tb, w.y, s1);
                r2 = fmaf(ta, w.z, r2); s2 = fmaf(tb, w.z, s2);
            }
        }
    }
    r0 += db3[0]; r1 += db3[1]; r2 += db3[2];
    s0 += db3[0]; s1 += db3[1]; s2 += db3[2];

    out[n0*FIN + 0] = r0;
    out[n0*FIN + 1] = r1;
    out[n0*FIN + 2] = r2;
    out[n1*FIN + 0] = s0;
    out[n1*FIN + 1] = s1;
    out[n1*FIN + 2] = s2;
}

__global__ void finalize_kernel(float* out, const float* loss_ws) {
    out[NTOK*FIN] = 1.25f * loss_ws[0] * (1.0f / (float)(NTOK*EMB));
}

extern "C" void kernel_launch(void* const* d_in, const int* in_sizes, int n_in,
                              void* d_out, int out_size, void* d_ws, size_t ws_size,
                              hipStream_t stream) {
    (void)in_sizes; (void)n_in; (void)ws_size; (void)out_size;
    float* ws = (float*)d_ws;
    hipMemsetAsync(ws, 0, sizeof(float), stream);   // ws re-poisoned each call

    vqvae_fused<<<NTOK/(2*TPB), TPB, 0, stream>>>(
        (const float*)d_in[0], (const float*)d_in[1], (const float*)d_in[2],
        (const float*)d_in[3], (const float*)d_in[4], (const float*)d_in[5],
        (const float*)d_in[6], (const float*)d_in[7], (const float*)d_in[8],
        (const float*)d_in[9], (const float*)d_in[10], (const float*)d_in[11],
        (const float*)d_in[12], (const float*)d_in[13], (const float*)d_in[14],
        (const float*)d_in[15],
        (float*)d_out, ws);

    finalize_kernel<<<1, 1, 0, stream>>>((float*)d_out, ws);
}